// Round 5
// baseline (182.267 us; speedup 1.0000x reference)
//
#include <hip/hip_runtime.h>
#include <hip/hip_bf16.h>

#define BATCH 8
#define CH    64
#define CH2   32
#define NN    4096
#define BN    (BATCH * NN)   // 32768 rows total

typedef __attribute__((ext_vector_type(8))) short  short8;   // 8 bf16 (MFMA A/B frag)
typedef __attribute__((ext_vector_type(4))) float  floatx4;  // MFMA C/D frag
typedef unsigned short ushort_t;

#define LOG2E 1.4426950408889634f

__device__ __forceinline__ unsigned short f2bf_rne(float f) {
    unsigned int u = __float_as_uint(f);
    return (unsigned short)((u + 0x7FFFu + ((u >> 16) & 1u)) >> 16);
}
// round-half-up: 2 VALU ops, fine for P in (0,1]
__device__ __forceinline__ unsigned short f2bf_fast(float f) {
    unsigned int u = __float_as_uint(f);
    return (unsigned short)((u + 0x8000u) >> 16);
}

// ---- fused prep: one pass over x produces
//   xT [B*N][64] bf16, mlog[row] = 12*||x_row||*log2e, gxT [B][32][N] bf16.
// 4 threads per row (16 ch each); 512 blocks x 256.
__global__ __launch_bounds__(256) void prep_fused(const float* __restrict__ x,
                                                  const float* __restrict__ gw,
                                                  const float* __restrict__ gb,
                                                  ushort_t* __restrict__ xT,
                                                  float* __restrict__ mlog,
                                                  ushort_t* __restrict__ gxT) {
    __shared__ float gwl[CH2 * CH];   // [o][c]
    __shared__ float gbl[CH2];
    int t = threadIdx.x;
    for (int i = t; i < CH2 * CH; i += 256) gwl[i] = gw[i];
    if (t < CH2) gbl[t] = gb[t];
    __syncthreads();

    int g   = blockIdx.x * 256 + t;
    int row = g >> 2;
    int q4  = g & 3;
    int b = row >> 12, n = row & (NN - 1);
    const float* xp = x + (size_t)b * CH * NN + n;

    float xv[16];
    float ns = 0.f;
    short8 v0, v1;
    #pragma unroll
    for (int j = 0; j < 8; ++j) {
        float a = xp[(size_t)(q4 * 16 + j) * NN];
        xv[j] = a; ns += a * a;
        v0[j] = (short)f2bf_rne(a);
    }
    #pragma unroll
    for (int j = 0; j < 8; ++j) {
        float a = xp[(size_t)(q4 * 16 + 8 + j) * NN];
        xv[8 + j] = a; ns += a * a;
        v1[j] = (short)f2bf_rne(a);
    }
    *(short8*)(xT + (size_t)row * CH + q4 * 16)     = v0;
    *(short8*)(xT + (size_t)row * CH + q4 * 16 + 8) = v1;
    ns += __shfl_xor(ns, 1);
    ns += __shfl_xor(ns, 2);
    if (q4 == 0) mlog[row] = 12.0f * sqrtf(ns) * LOG2E;

    // gx: partial over this thread's 16 channels, then xor-reduce across the 4 row-threads
    float acc[CH2];
    #pragma unroll
    for (int o = 0; o < CH2; ++o) acc[o] = 0.f;
    #pragma unroll
    for (int j = 0; j < 16; ++j) {
        float a = xv[j];
        const float* gc = gwl + q4 * 16 + j;
        #pragma unroll
        for (int o = 0; o < CH2; ++o) acc[o] = fmaf(gc[o * CH], a, acc[o]);
    }
    #pragma unroll
    for (int o = 0; o < CH2; ++o) {
        acc[o] += __shfl_xor(acc[o], 1);
        acc[o] += __shfl_xor(acc[o], 2);
    }
    // each of the 4 threads writes 8 output channels for this column n
    #pragma unroll
    for (int i = 0; i < 8; ++i) {
        int o = q4 * 8 + i;
        gxT[((size_t)b * CH2 + o) * NN + n] = f2bf_rne(acc[o] + gbl[o]);
    }
}

// ---- flash attention: single-buffered K tile in LDS (2 barriers/iter), V frags
// from global (L2-resident), 32 q-rows/wave, fixed per-row softmax shift, split-K.
// grid = 256 * split blocks, 256 threads (4 waves). LDS 27.6 KB -> 5 blocks/CU.
__global__ __launch_bounds__(256, 5) void flash_attn(const ushort_t* __restrict__ xT,
                                                     const ushort_t* __restrict__ gxT,
                                                     const float* __restrict__ mlog,
                                                     float* __restrict__ py,
                                                     float* __restrict__ pl,
                                                     int ksplit) {
    __shared__ ushort_t Klds[64 * 72];      // key tile [key][ch], stride 72
    __shared__ ushort_t Plds[4][32 * 72];   // per-wave P [row][key], stride 72

    const int tid = threadIdx.x, wave = tid >> 6, lane = tid & 63;
    const int ql = lane & 15, quad = lane >> 4;
    const int bq = blockIdx.x & 255;        // 256 = 8 batches * 32 qtiles(128)
    const int sp = blockIdx.x >> 8;
    const int b = bq >> 5, qt = bq & 31;
    const int n0 = qt * 128 + wave * 32;
    const int k0 = sp * ksplit;

    short8 qf[2][2];
    float mlr[2][4];
    #pragma unroll
    for (int rg = 0; rg < 2; ++rg) {
        const ushort_t* qp = xT + ((size_t)(b * NN + n0 + rg * 16 + ql)) * CH + quad * 8;
        qf[rg][0] = *(const short8*)qp;
        qf[rg][1] = *(const short8*)(qp + 32);
        float4 m4 = *(const float4*)(mlog + (size_t)b * NN + n0 + rg * 16 + quad * 4);
        mlr[rg][0] = m4.x; mlr[rg][1] = m4.y; mlr[rg][2] = m4.z; mlr[rg][3] = m4.w;
    }

    floatx4 yf[2][2];
    float rs[2][4];
    #pragma unroll
    for (int rg = 0; rg < 2; ++rg) {
        yf[rg][0] = (floatx4){0.f, 0.f, 0.f, 0.f};
        yf[rg][1] = (floatx4){0.f, 0.f, 0.f, 0.f};
        #pragma unroll
        for (int r = 0; r < 4; ++r) rs[rg][r] = 0.f;
    }

    const ushort_t* kb = xT + (size_t)(b * NN + k0) * CH;
    const ushort_t* vb = gxT + (size_t)b * CH2 * NN + k0;
    ushort_t* Pw = Plds[wave];
    const int iters = ksplit >> 6;

    const int skey = tid >> 3;              // staging: rows skey and skey+32
    const int sc0  = (tid & 7) * 8;

    for (int kt = 0; kt < iters; ++kt) {
        // issue this tile's global loads first; vmcnt waits land at first use
        short8 kv0 = *(const short8*)(kb + ((size_t)kt << 12) + (size_t)skey * CH + sc0);
        short8 kv1 = *(const short8*)(kb + ((size_t)kt << 12) + (size_t)(skey + 32) * CH + sc0);
        short8 vf[2][2];
        #pragma unroll
        for (int ss = 0; ss < 2; ++ss)
            #pragma unroll
            for (int h = 0; h < 2; ++h)
                vf[ss][h] = *(const short8*)(vb + (size_t)(h * 16 + ql) * NN +
                                             kt * 64 + ss * 32 + quad * 8);

        __syncthreads();   // all waves done reading previous K tile
        *(short8*)(&Klds[(size_t)skey * 72 + sc0])        = kv0;
        *(short8*)(&Klds[(size_t)(skey + 32) * 72 + sc0]) = kv1;
        __syncthreads();

        // QK^T + exp: K frags from LDS, shared across both row-groups
        #pragma unroll
        for (int ct = 0; ct < 4; ++ct) {
            const ushort_t* kp = Klds + (ct * 16 + ql) * 72 + quad * 8;
            short8 kf0 = *(const short8*)kp;
            short8 kf1 = *(const short8*)(kp + 32);
            #pragma unroll
            for (int rg = 0; rg < 2; ++rg) {
                floatx4 s = (floatx4){0.f, 0.f, 0.f, 0.f};
                s = __builtin_amdgcn_mfma_f32_16x16x32_bf16(qf[rg][0], kf0, s, 0, 0, 0);
                s = __builtin_amdgcn_mfma_f32_16x16x32_bf16(qf[rg][1], kf1, s, 0, 0, 0);
                #pragma unroll
                for (int r = 0; r < 4; ++r) {
                    float p = __builtin_amdgcn_exp2f(fmaf(s[r], LOG2E, -mlr[rg][r]));
                    rs[rg][r] += p;
                    Pw[(rg * 16 + quad * 4 + r) * 72 + ct * 16 + ql] = f2bf_fast(p);
                }
            }
        }

        // PV: y[rg][16 rows][32 och] += P[16][64] * V[64][32]
        #pragma unroll
        for (int rg = 0; rg < 2; ++rg)
            #pragma unroll
            for (int ss = 0; ss < 2; ++ss) {
                short8 pf = *(const short8*)(Pw + (rg * 16 + ql) * 72 + ss * 32 + quad * 8);
                #pragma unroll
                for (int h = 0; h < 2; ++h)
                    yf[rg][h] = __builtin_amdgcn_mfma_f32_16x16x32_bf16(pf, vf[ss][h],
                                                                        yf[rg][h], 0, 0, 0);
            }
    }

    // epilogue: reduce l across the 16 key-lanes, write partials
    #pragma unroll
    for (int rg = 0; rg < 2; ++rg)
        #pragma unroll
        for (int r = 0; r < 4; ++r) {
            rs[rg][r] += __shfl_xor(rs[rg][r], 1);
            rs[rg][r] += __shfl_xor(rs[rg][r], 2);
            rs[rg][r] += __shfl_xor(rs[rg][r], 4);
            rs[rg][r] += __shfl_xor(rs[rg][r], 8);
        }
    #pragma unroll
    for (int rg = 0; rg < 2; ++rg) {
        size_t rowg = (size_t)b * NN + n0 + rg * 16 + quad * 4;
        #pragma unroll
        for (int r = 0; r < 4; ++r) {
            #pragma unroll
            for (int h = 0; h < 2; ++h)
                py[((size_t)sp * BN + rowg + r) * CH2 + h * 16 + ql] = yf[rg][h][r];
            if (ql == 0) pl[(size_t)sp * BN + rowg + r] = rs[rg][r];
        }
    }
}

// ---- reduction over splits + normalize + output projection + bias + residual
// 256 blocks x 128 threads; block handles 128 consecutive rows, fully coalesced.
__global__ __launch_bounds__(128) void reduce_proj(const float* __restrict__ py,
                                                   const float* __restrict__ pl,
                                                   const float* __restrict__ Ww,
                                                   const float* __restrict__ Wb,
                                                   const float* __restrict__ x,
                                                   float* __restrict__ out,
                                                   int nsplit) {
    __shared__ float WwL[CH * 33];
    __shared__ float WbL[CH];
    __shared__ float linv[128];
    __shared__ float Y[128 * 33];           // [row][och], +1 pad
    int t = threadIdx.x;
    for (int i = t; i < CH * CH2; i += 128) WwL[(i >> 5) * 33 + (i & 31)] = Ww[i];
    if (t < CH) WbL[t] = Wb[t];

    int row0 = blockIdx.x * 128;
    float4 acc4[8];
    #pragma unroll
    for (int c = 0; c < 8; ++c) acc4[c] = (float4){0.f, 0.f, 0.f, 0.f};
    float l = 0.f;
    for (int s = 0; s < nsplit; ++s) {
        l += pl[(size_t)s * BN + row0 + t];
        const float4* p4 = (const float4*)(py + ((size_t)s * BN + row0) * CH2);
        #pragma unroll
        for (int c = 0; c < 8; ++c) {
            float4 v = p4[c * 128 + t];     // fully coalesced
            acc4[c].x += v.x; acc4[c].y += v.y; acc4[c].z += v.z; acc4[c].w += v.w;
        }
    }
    linv[t] = 1.0f / l;
    __syncthreads();
    #pragma unroll
    for (int c = 0; c < 8; ++c) {
        int f = c * 128 + t;
        int r = f >> 3, o = f & 7;          // row within block, float4 slot
        float sc = linv[r];
        Y[r * 33 + o * 4 + 0] = acc4[c].x * sc;
        Y[r * 33 + o * 4 + 1] = acc4[c].y * sc;
        Y[r * 33 + o * 4 + 2] = acc4[c].z * sc;
        Y[r * 33 + o * 4 + 3] = acc4[c].w * sc;
    }
    __syncthreads();

    float y[CH2];
    #pragma unroll
    for (int o = 0; o < CH2; ++o) y[o] = Y[t * 33 + o];
    int g = row0 + t, b = g >> 12, n = g & (NN - 1);
    #pragma unroll
    for (int c = 0; c < CH; ++c) {
        float acc = WbL[c];
        #pragma unroll
        for (int o = 0; o < CH2; ++o) acc = fmaf(WwL[c * 33 + o], y[o], acc);
        size_t oi = ((size_t)b * CH + c) * NN + n;
        out[oi] = acc + x[oi];              // coalesced: lanes span consecutive n
    }
}

extern "C" void kernel_launch(void* const* d_in, const int* in_sizes, int n_in,
                              void* d_out, int out_size, void* d_ws, size_t ws_size,
                              hipStream_t stream) {
    const float* x  = (const float*)d_in[0];
    const float* gw = (const float*)d_in[1];
    const float* gb = (const float*)d_in[2];
    const float* Ww = (const float*)d_in[3];
    const float* Wb = (const float*)d_in[4];
    float* out = (float*)d_out;

    // workspace layout
    ushort_t* xT   = (ushort_t*)d_ws;                          // BN*64 bf16   = 4 MB
    ushort_t* gxT  = xT + (size_t)BN * CH;                     // B*32*N bf16  = 2 MB
    float*    mlog = (float*)(gxT + (size_t)BATCH * CH2 * NN); // BN fp32      = 128 KB
    float*    py   = mlog + BN;                                // split*BN*32 fp32
    size_t base_bytes = (size_t)BN * CH * 2 + (size_t)BATCH * CH2 * NN * 2 + (size_t)BN * 4;
    int split = 8;
    while (split > 1 && base_bytes + (size_t)split * BN * (CH2 + 1) * 4 > ws_size)
        split >>= 1;
    float* pl = py + (size_t)split * BN * CH2;

    hipLaunchKernelGGL(prep_fused,  dim3(BN * 4 / 256), dim3(256), 0, stream,
                       x, gw, gb, xT, mlog, gxT);
    hipLaunchKernelGGL(flash_attn,  dim3(256 * split),  dim3(256), 0, stream,
                       xT, gxT, mlog, py, pl, NN / split);
    hipLaunchKernelGGL(reduce_proj, dim3(BN / 128),     dim3(128), 0, stream,
                       py, pl, Ww, Wb, x, out, split);
}

// Round 6
// 171.658 us; speedup vs baseline: 1.0618x; 1.0618x over previous
//
#include <hip/hip_runtime.h>
#include <hip/hip_bf16.h>

#define BATCH 8
#define CH    64
#define CH2   32
#define NN    4096
#define BN    (BATCH * NN)   // 32768 rows total
#define KPAD  72             // LDS key-tile row stride (elements)
#define YPAD  36             // epilogue transpose row stride (floats, 16B-aligned)

typedef __attribute__((ext_vector_type(8)))  short        short8;    // 8 bf16 (MFMA A/B frag)
typedef __attribute__((ext_vector_type(16))) float        floatx16;  // 32x32 MFMA C/D frag
typedef __attribute__((ext_vector_type(4)))  unsigned int uint4v;
typedef __attribute__((ext_vector_type(8)))  unsigned short ushort8v;
typedef unsigned short ushort_t;

#define LOG2E 1.4426950408889634f

__device__ __forceinline__ unsigned short f2bf_rne(float f) {
    unsigned int u = __float_as_uint(f);
    return (unsigned short)((u + 0x7FFFu + ((u >> 16) & 1u)) >> 16);
}

// ---- fused prep: one pass over x produces
//   xT [B*N][64] bf16, mlog[row] = 12*||x_row||*log2e, gxT [B][32][N] bf16.
__global__ __launch_bounds__(256) void prep_fused(const float* __restrict__ x,
                                                  const float* __restrict__ gw,
                                                  const float* __restrict__ gb,
                                                  ushort_t* __restrict__ xT,
                                                  float* __restrict__ mlog,
                                                  ushort_t* __restrict__ gxT) {
    __shared__ float gwl[CH2 * CH];   // [o][c]
    __shared__ float gbl[CH2];
    int t = threadIdx.x;
    for (int i = t; i < CH2 * CH; i += 256) gwl[i] = gw[i];
    if (t < CH2) gbl[t] = gb[t];
    __syncthreads();

    int g   = blockIdx.x * 256 + t;
    int row = g >> 2;
    int q4  = g & 3;
    int b = row >> 12, n = row & (NN - 1);
    const float* xp = x + (size_t)b * CH * NN + n;

    float xv[16];
    float ns = 0.f;
    short8 v0, v1;
    #pragma unroll
    for (int j = 0; j < 8; ++j) {
        float a = xp[(size_t)(q4 * 16 + j) * NN];
        xv[j] = a; ns += a * a;
        v0[j] = (short)f2bf_rne(a);
    }
    #pragma unroll
    for (int j = 0; j < 8; ++j) {
        float a = xp[(size_t)(q4 * 16 + 8 + j) * NN];
        xv[8 + j] = a; ns += a * a;
        v1[j] = (short)f2bf_rne(a);
    }
    *(short8*)(xT + (size_t)row * CH + q4 * 16)     = v0;
    *(short8*)(xT + (size_t)row * CH + q4 * 16 + 8) = v1;
    ns += __shfl_xor(ns, 1);
    ns += __shfl_xor(ns, 2);
    if (q4 == 0) mlog[row] = 12.0f * sqrtf(ns) * LOG2E;

    float acc[CH2];
    #pragma unroll
    for (int o = 0; o < CH2; ++o) acc[o] = 0.f;
    #pragma unroll
    for (int j = 0; j < 16; ++j) {
        float a = xv[j];
        const float* gc = gwl + q4 * 16 + j;
        #pragma unroll
        for (int o = 0; o < CH2; ++o) acc[o] = fmaf(gc[o * CH], a, acc[o]);
    }
    #pragma unroll
    for (int o = 0; o < CH2; ++o) {
        acc[o] += __shfl_xor(acc[o], 1);
        acc[o] += __shfl_xor(acc[o], 2);
    }
    #pragma unroll
    for (int i = 0; i < 8; ++i) {
        int o = q4 * 8 + i;
        gxT[((size_t)b * CH2 + o) * NN + n] = f2bf_rne(acc[o] + gbl[o]);
    }
}

// ---- flash attention, S^T formulation (32x32x16 MFMA):
//   S^T = K·Q^T  (C-layout: row=key, col=q)
//   P^T B-operand built in-register: pack bf16 + shfl_xor(32) + select (no LDS roundtrip)
//   y^T = V^T·P^T accumulated in one 32x32 C-frag per wave (32 q-rows/wave).
// LDS: K tile only (staged, 2 barriers/iter) + epilogue transpose buffer.
// grid = 256 * split blocks, 256 threads (4 waves).
__global__ __launch_bounds__(256, 4) void flash_attn(const ushort_t* __restrict__ xT,
                                                     const ushort_t* __restrict__ gxT,
                                                     const float* __restrict__ mlog,
                                                     ushort_t* __restrict__ py,
                                                     float* __restrict__ pl,
                                                     int ksplit) {
    __shared__ ushort_t Klds[64 * KPAD];        // 9.2 KB
    __shared__ float    Ybuf[4][32 * YPAD];     // 18.4 KB (epilogue only)

    const int tid = threadIdx.x, wave = tid >> 6, lane = tid & 63;
    const int q5 = lane & 31;          // q index (B/D cols) or o index (V A-operand)
    const int h  = lane >> 5;          // half-wave: k-group selector
    const int bq = blockIdx.x & 255;   // 256 = 8 batches * 32 qtiles(128)
    const int sp = blockIdx.x >> 8;
    const int b = bq >> 5, qt = bq & 31;
    const int n0 = qt * 128 + wave * 32;
    const int k0 = sp * ksplit;

    // Q as B-operand: B[k=c][n=q]: lane holds q=q5, c = f*16 + h*8 + j
    short8 qf[4];
    {
        const ushort_t* qp = xT + ((size_t)(b * NN + n0 + q5)) * CH + h * 8;
        #pragma unroll
        for (int f = 0; f < 4; ++f) qf[f] = *(const short8*)(qp + f * 16);
    }
    const float ml = mlog[(size_t)b * NN + n0 + q5];

    floatx16 yt;
    #pragma unroll
    for (int i = 0; i < 16; ++i) yt[i] = 0.f;
    float rs = 0.f;

    const ushort_t* kb = xT + (size_t)(b * NN + k0) * CH;
    const ushort_t* vb = gxT + (size_t)b * CH2 * NN + k0;
    const int iters = ksplit >> 6;
    const int skey = tid >> 3, sc0 = (tid & 7) * 8;

    for (int kt = 0; kt < iters; ++kt) {
        // issue this tile's global loads first; vmcnt waits land at first use
        short8 kv0 = *(const short8*)(kb + ((size_t)kt << 12) + (size_t)skey * CH + sc0);
        short8 kv1 = *(const short8*)(kb + ((size_t)kt << 12) + (size_t)(skey + 32) * CH + sc0);
        // V as A-operand: A[m=o][k=key]: lane o=q5, key = kt*64 + fr*16 + h*8 + j
        short8 vf[4];
        #pragma unroll
        for (int fr = 0; fr < 4; ++fr)
            vf[fr] = *(const short8*)(vb + (size_t)q5 * NN + kt * 64 + fr * 16 + h * 8);

        __syncthreads();
        *(short8*)(&Klds[skey * KPAD + sc0])        = kv0;
        *(short8*)(&Klds[(skey + 32) * KPAD + sc0]) = kv1;
        __syncthreads();

        #pragma unroll
        for (int T = 0; T < 2; ++T) {
            // S^T tile: keys T*32..T*32+31 x 32 q. A=K frag: lane key=q5, c=f*16+h*8+j
            floatx16 st;
            #pragma unroll
            for (int i = 0; i < 16; ++i) st[i] = 0.f;
            #pragma unroll
            for (int f = 0; f < 4; ++f) {
                short8 kf = *(const short8*)(&Klds[(T * 32 + q5) * KPAD + f * 16 + h * 8]);
                st = __builtin_amdgcn_mfma_f32_32x32x16_bf16(kf, qf[f], st, 0, 0, 0);
            }
            // exp + l-partial + pack pairs (lane's rows: (r&3)+8*(r>>2)+4h)
            unsigned int d[8];
            #pragma unroll
            for (int r2 = 0; r2 < 8; ++r2) {
                float p0 = __builtin_amdgcn_exp2f(fmaf(st[2 * r2],     LOG2E, -ml));
                float p1 = __builtin_amdgcn_exp2f(fmaf(st[2 * r2 + 1], LOG2E, -ml));
                rs += p0; rs += p1;
                d[r2] = ((__float_as_uint(p0) + 0x8000u) >> 16) |
                        ((__float_as_uint(p1) + 0x8000u) & 0xFFFF0000u);
            }
            // P^T B-frags for the two 16-key halves: butterfly across lane^32 + select
            #pragma unroll
            for (int fp = 0; fp < 2; ++fp) {
                unsigned int d0 = d[fp * 4 + 0], d1 = d[fp * 4 + 1];
                unsigned int d2 = d[fp * 4 + 2], d3 = d[fp * 4 + 3];
                unsigned int e0 = (unsigned int)__shfl_xor((int)d0, 32);
                unsigned int e1 = (unsigned int)__shfl_xor((int)d1, 32);
                unsigned int e2 = (unsigned int)__shfl_xor((int)d2, 32);
                unsigned int e3 = (unsigned int)__shfl_xor((int)d3, 32);
                uint4v bv;
                bv[0] = h ? e2 : d0;
                bv[1] = h ? e3 : d1;
                bv[2] = h ? d2 : e0;
                bv[3] = h ? d3 : e1;
                short8 pb = __builtin_bit_cast(short8, bv);
                yt = __builtin_amdgcn_mfma_f32_32x32x16_bf16(vf[T * 2 + fp], pb, yt, 0, 0, 0);
            }
        }
    }

    // epilogue: finish l, transpose y^T via LDS, write coalesced bf16 partials
    rs += __shfl_xor(rs, 32);
    float* yb = Ybuf[wave];
    #pragma unroll
    for (int reg = 0; reg < 16; ++reg) {
        int o = (reg & 3) + 8 * (reg >> 2) + 4 * h;
        yb[q5 * YPAD + o] = yt[reg];
    }
    __syncthreads();
    {
        int qq = lane >> 1, half = lane & 1;
        const float* src = yb + qq * YPAD + half * 16;
        float4 s0 = *(const float4*)(src);
        float4 s1 = *(const float4*)(src + 4);
        float4 s2 = *(const float4*)(src + 8);
        float4 s3 = *(const float4*)(src + 12);
        ushort8v pk0, pk1;
        pk0[0] = f2bf_rne(s0.x); pk0[1] = f2bf_rne(s0.y);
        pk0[2] = f2bf_rne(s0.z); pk0[3] = f2bf_rne(s0.w);
        pk0[4] = f2bf_rne(s1.x); pk0[5] = f2bf_rne(s1.y);
        pk0[6] = f2bf_rne(s1.z); pk0[7] = f2bf_rne(s1.w);
        pk1[0] = f2bf_rne(s2.x); pk1[1] = f2bf_rne(s2.y);
        pk1[2] = f2bf_rne(s2.z); pk1[3] = f2bf_rne(s2.w);
        pk1[4] = f2bf_rne(s3.x); pk1[5] = f2bf_rne(s3.y);
        pk1[6] = f2bf_rne(s3.z); pk1[7] = f2bf_rne(s3.w);
        ushort_t* dst = py + ((size_t)sp * BN + (size_t)b * NN + n0 + qq) * CH2 + half * 16;
        *(ushort8v*)(dst)     = pk0;
        *(ushort8v*)(dst + 8) = pk1;
    }
    if (h == 0) pl[(size_t)sp * BN + (size_t)b * NN + n0 + q5] = rs;
}

// ---- reduction over splits + normalize + output projection + bias + residual
// 1 thread per row; 256 blocks x 128 threads; everything register-resident.
__global__ __launch_bounds__(128) void reduce_proj(const ushort_t* __restrict__ py,
                                                   const float* __restrict__ pl,
                                                   const float* __restrict__ Ww,
                                                   const float* __restrict__ Wb,
                                                   const float* __restrict__ x,
                                                   float* __restrict__ out,
                                                   int nsplit) {
    __shared__ float WwL[CH * 33];
    __shared__ float WbL[CH];
    int t = threadIdx.x;
    for (int i = t; i < CH * CH2; i += 128) WwL[(i >> 5) * 33 + (i & 31)] = Ww[i];
    if (t < CH) WbL[t] = Wb[t];
    __syncthreads();

    int g = blockIdx.x * 128 + t;       // global row
    int b = g >> 12, n = g & (NN - 1);
    float y[CH2];
    #pragma unroll
    for (int o = 0; o < CH2; ++o) y[o] = 0.f;
    float l = 0.f;
    for (int s = 0; s < nsplit; ++s) {
        l += pl[(size_t)s * BN + g];
        const ushort8v* p8 = (const ushort8v*)(py + ((size_t)s * BN + g) * CH2);
        #pragma unroll
        for (int c = 0; c < 4; ++c) {
            ushort8v v = p8[c];
            #pragma unroll
            for (int j = 0; j < 8; ++j)
                y[c * 8 + j] += __uint_as_float((unsigned int)v[j] << 16);
        }
    }
    float inv = 1.0f / l;
    #pragma unroll
    for (int o = 0; o < CH2; ++o) y[o] *= inv;
    #pragma unroll
    for (int c = 0; c < CH; ++c) {
        float acc = WbL[c];
        #pragma unroll
        for (int o = 0; o < CH2; ++o) acc = fmaf(WwL[c * 33 + o], y[o], acc);
        size_t oi = ((size_t)b * CH + c) * NN + n;
        out[oi] = acc + x[oi];          // coalesced: lanes span consecutive n
    }
}

extern "C" void kernel_launch(void* const* d_in, const int* in_sizes, int n_in,
                              void* d_out, int out_size, void* d_ws, size_t ws_size,
                              hipStream_t stream) {
    const float* x  = (const float*)d_in[0];
    const float* gw = (const float*)d_in[1];
    const float* gb = (const float*)d_in[2];
    const float* Ww = (const float*)d_in[3];
    const float* Wb = (const float*)d_in[4];
    float* out = (float*)d_out;

    // workspace layout (kept small: harness re-poisons all of d_ws every launch)
    ushort_t* xT   = (ushort_t*)d_ws;                          // 4 MB
    ushort_t* gxT  = xT + (size_t)BN * CH;                     // 2 MB
    float*    mlog = (float*)(gxT + (size_t)BATCH * CH2 * NN); // 128 KB
    ushort_t* py   = (ushort_t*)(mlog + BN);                   // split*BN*32 bf16
    size_t base_bytes = (size_t)BN * CH * 2 + (size_t)BATCH * CH2 * NN * 2 + (size_t)BN * 4;
    int split = 4;
    while (split > 1 && base_bytes + (size_t)split * BN * (CH2 * 2 + 4) > ws_size)
        split >>= 1;
    float* pl = (float*)(py + (size_t)split * BN * CH2);

    hipLaunchKernelGGL(prep_fused,  dim3(BN * 4 / 256), dim3(256), 0, stream,
                       x, gw, gb, xT, mlog, gxT);
    hipLaunchKernelGGL(flash_attn,  dim3(256 * split),  dim3(256), 0, stream,
                       xT, gxT, mlog, py, pl, NN / split);
    hipLaunchKernelGGL(reduce_proj, dim3(BN / 128),     dim3(128), 0, stream,
                       py, pl, Ww, Wb, x, out, split);
}

// Round 7
// 126.572 us; speedup vs baseline: 1.4400x; 1.3562x over previous
//
#include <hip/hip_runtime.h>
#include <hip/hip_bf16.h>

#define BATCH 8
#define CH    64
#define CH2   32
#define NN    4096
#define BN    (BATCH * NN)   // 32768 rows total
#define KPAD  72             // LDS key-tile row stride (elements)
#define YPAD  36             // flash epilogue transpose row stride (floats)
#define RPAD  40             // reduce_proj LDS row stride (bf16 elements, 16B-aligned)

typedef __attribute__((ext_vector_type(8)))  short        short8;    // 8 bf16 (MFMA A/B frag)
typedef __attribute__((ext_vector_type(4)))  float        floatx4;   // 16x16 MFMA C/D frag
typedef __attribute__((ext_vector_type(16))) float        floatx16;  // 32x32 MFMA C/D frag
typedef __attribute__((ext_vector_type(4)))  unsigned int uint4v;
typedef __attribute__((ext_vector_type(8)))  unsigned short ushort8v;
typedef unsigned short ushort_t;

#define LOG2E 1.4426950408889634f

__device__ __forceinline__ unsigned short f2bf_rne(float f) {
    unsigned int u = __float_as_uint(f);
    return (unsigned short)((u + 0x7FFFu + ((u >> 16) & 1u)) >> 16);
}

// ---- fused prep: one pass over x produces
//   xT [B*N][64] bf16, mlog[row] = 12*||x_row||*log2e, gxT [B][32][N] bf16.
__global__ __launch_bounds__(256) void prep_fused(const float* __restrict__ x,
                                                  const float* __restrict__ gw,
                                                  const float* __restrict__ gb,
                                                  ushort_t* __restrict__ xT,
                                                  float* __restrict__ mlog,
                                                  ushort_t* __restrict__ gxT) {
    __shared__ float gwl[CH2 * CH];   // [o][c]
    __shared__ float gbl[CH2];
    int t = threadIdx.x;
    for (int i = t; i < CH2 * CH; i += 256) gwl[i] = gw[i];
    if (t < CH2) gbl[t] = gb[t];
    __syncthreads();

    int g   = blockIdx.x * 256 + t;
    int row = g >> 2;
    int q4  = g & 3;
    int b = row >> 12, n = row & (NN - 1);
    const float* xp = x + (size_t)b * CH * NN + n;

    float xv[16];
    float ns = 0.f;
    short8 v0, v1;
    #pragma unroll
    for (int j = 0; j < 8; ++j) {
        float a = xp[(size_t)(q4 * 16 + j) * NN];
        xv[j] = a; ns += a * a;
        v0[j] = (short)f2bf_rne(a);
    }
    #pragma unroll
    for (int j = 0; j < 8; ++j) {
        float a = xp[(size_t)(q4 * 16 + 8 + j) * NN];
        xv[8 + j] = a; ns += a * a;
        v1[j] = (short)f2bf_rne(a);
    }
    *(short8*)(xT + (size_t)row * CH + q4 * 16)     = v0;
    *(short8*)(xT + (size_t)row * CH + q4 * 16 + 8) = v1;
    ns += __shfl_xor(ns, 1);
    ns += __shfl_xor(ns, 2);
    if (q4 == 0) mlog[row] = 12.0f * sqrtf(ns) * LOG2E;

    float acc[CH2];
    #pragma unroll
    for (int o = 0; o < CH2; ++o) acc[o] = 0.f;
    #pragma unroll
    for (int j = 0; j < 16; ++j) {
        float a = xv[j];
        const float* gc = gwl + q4 * 16 + j;
        #pragma unroll
        for (int o = 0; o < CH2; ++o) acc[o] = fmaf(gc[o * CH], a, acc[o]);
    }
    #pragma unroll
    for (int o = 0; o < CH2; ++o) {
        acc[o] += __shfl_xor(acc[o], 1);
        acc[o] += __shfl_xor(acc[o], 2);
    }
    #pragma unroll
    for (int i = 0; i < 8; ++i) {
        int o = q4 * 8 + i;
        gxT[((size_t)b * CH2 + o) * NN + n] = f2bf_rne(acc[o] + gbl[o]);
    }
}

// ---- flash attention, S^T formulation (32x32x16 MFMA), unchanged from R6 ----
__global__ __launch_bounds__(256, 4) void flash_attn(const ushort_t* __restrict__ xT,
                                                     const ushort_t* __restrict__ gxT,
                                                     const float* __restrict__ mlog,
                                                     ushort_t* __restrict__ py,
                                                     float* __restrict__ pl,
                                                     int ksplit) {
    __shared__ ushort_t Klds[64 * KPAD];        // 9.2 KB
    __shared__ float    Ybuf[4][32 * YPAD];     // 18.4 KB (epilogue only)

    const int tid = threadIdx.x, wave = tid >> 6, lane = tid & 63;
    const int q5 = lane & 31;
    const int h  = lane >> 5;
    const int bq = blockIdx.x & 255;
    const int sp = blockIdx.x >> 8;
    const int b = bq >> 5, qt = bq & 31;
    const int n0 = qt * 128 + wave * 32;
    const int k0 = sp * ksplit;

    short8 qf[4];
    {
        const ushort_t* qp = xT + ((size_t)(b * NN + n0 + q5)) * CH + h * 8;
        #pragma unroll
        for (int f = 0; f < 4; ++f) qf[f] = *(const short8*)(qp + f * 16);
    }
    const float ml = mlog[(size_t)b * NN + n0 + q5];

    floatx16 yt;
    #pragma unroll
    for (int i = 0; i < 16; ++i) yt[i] = 0.f;
    float rs = 0.f;

    const ushort_t* kb = xT + (size_t)(b * NN + k0) * CH;
    const ushort_t* vb = gxT + (size_t)b * CH2 * NN + k0;
    const int iters = ksplit >> 6;
    const int skey = tid >> 3, sc0 = (tid & 7) * 8;

    for (int kt = 0; kt < iters; ++kt) {
        short8 kv0 = *(const short8*)(kb + ((size_t)kt << 12) + (size_t)skey * CH + sc0);
        short8 kv1 = *(const short8*)(kb + ((size_t)kt << 12) + (size_t)(skey + 32) * CH + sc0);
        short8 vf[4];
        #pragma unroll
        for (int fr = 0; fr < 4; ++fr)
            vf[fr] = *(const short8*)(vb + (size_t)q5 * NN + kt * 64 + fr * 16 + h * 8);

        __syncthreads();
        *(short8*)(&Klds[skey * KPAD + sc0])        = kv0;
        *(short8*)(&Klds[(skey + 32) * KPAD + sc0]) = kv1;
        __syncthreads();

        #pragma unroll
        for (int T = 0; T < 2; ++T) {
            floatx16 st;
            #pragma unroll
            for (int i = 0; i < 16; ++i) st[i] = 0.f;
            #pragma unroll
            for (int f = 0; f < 4; ++f) {
                short8 kf = *(const short8*)(&Klds[(T * 32 + q5) * KPAD + f * 16 + h * 8]);
                st = __builtin_amdgcn_mfma_f32_32x32x16_bf16(kf, qf[f], st, 0, 0, 0);
            }
            unsigned int d[8];
            #pragma unroll
            for (int r2 = 0; r2 < 8; ++r2) {
                float p0 = __builtin_amdgcn_exp2f(fmaf(st[2 * r2],     LOG2E, -ml));
                float p1 = __builtin_amdgcn_exp2f(fmaf(st[2 * r2 + 1], LOG2E, -ml));
                rs += p0; rs += p1;
                d[r2] = ((__float_as_uint(p0) + 0x8000u) >> 16) |
                        ((__float_as_uint(p1) + 0x8000u) & 0xFFFF0000u);
            }
            #pragma unroll
            for (int fp = 0; fp < 2; ++fp) {
                unsigned int d0 = d[fp * 4 + 0], d1 = d[fp * 4 + 1];
                unsigned int d2 = d[fp * 4 + 2], d3 = d[fp * 4 + 3];
                unsigned int e0 = (unsigned int)__shfl_xor((int)d0, 32);
                unsigned int e1 = (unsigned int)__shfl_xor((int)d1, 32);
                unsigned int e2 = (unsigned int)__shfl_xor((int)d2, 32);
                unsigned int e3 = (unsigned int)__shfl_xor((int)d3, 32);
                uint4v bv;
                bv[0] = h ? e2 : d0;
                bv[1] = h ? e3 : d1;
                bv[2] = h ? d2 : e0;
                bv[3] = h ? d3 : e1;
                short8 pb = __builtin_bit_cast(short8, bv);
                yt = __builtin_amdgcn_mfma_f32_32x32x16_bf16(vf[T * 2 + fp], pb, yt, 0, 0, 0);
            }
        }
    }

    rs += __shfl_xor(rs, 32);
    float* yb = Ybuf[wave];
    #pragma unroll
    for (int reg = 0; reg < 16; ++reg) {
        int o = (reg & 3) + 8 * (reg >> 2) + 4 * h;
        yb[q5 * YPAD + o] = yt[reg];
    }
    __syncthreads();
    {
        int qq = lane >> 1, half = lane & 1;
        const float* src = yb + qq * YPAD + half * 16;
        float4 s0 = *(const float4*)(src);
        float4 s1 = *(const float4*)(src + 4);
        float4 s2 = *(const float4*)(src + 8);
        float4 s3 = *(const float4*)(src + 12);
        ushort8v pk0, pk1;
        pk0[0] = f2bf_rne(s0.x); pk0[1] = f2bf_rne(s0.y);
        pk0[2] = f2bf_rne(s0.z); pk0[3] = f2bf_rne(s0.w);
        pk0[4] = f2bf_rne(s1.x); pk0[5] = f2bf_rne(s1.y);
        pk0[6] = f2bf_rne(s1.z); pk0[7] = f2bf_rne(s1.w);
        pk1[0] = f2bf_rne(s2.x); pk1[1] = f2bf_rne(s2.y);
        pk1[2] = f2bf_rne(s2.z); pk1[3] = f2bf_rne(s2.w);
        pk1[4] = f2bf_rne(s3.x); pk1[5] = f2bf_rne(s3.y);
        pk1[6] = f2bf_rne(s3.z); pk1[7] = f2bf_rne(s3.w);
        ushort_t* dst = py + ((size_t)sp * BN + (size_t)b * NN + n0 + qq) * CH2 + half * 16;
        *(ushort8v*)(dst)     = pk0;
        *(ushort8v*)(dst + 8) = pk1;
    }
    if (h == 0) pl[(size_t)sp * BN + (size_t)b * NN + n0 + q5] = rs;
}

// ---- reduce+proj v2: two-phase, MFMA projection.
// Block = 256 threads (4 waves) handles 64 consecutive rows. Grid = BN/64 = 512.
// Phase 1: coalesced split-sum of py (bf16) -> normalize -> bf16 LDS tile Y.
// Phase 2: out[c][n] = Ww(bf16) @ Y^T via one K=32 MFMA per 16-c tile + bias + residual.
__global__ __launch_bounds__(256) void reduce_proj(const ushort_t* __restrict__ py,
                                                   const float* __restrict__ pl,
                                                   const float* __restrict__ Ww,
                                                   const float* __restrict__ Wb,
                                                   const float* __restrict__ x,
                                                   float* __restrict__ out,
                                                   int nsplit) {
    __shared__ ushort_t WwB[CH * RPAD];     // Ww bf16, [c][o], stride 40
    __shared__ ushort_t Y[64 * RPAD];       // y-hat bf16, [row][o], stride 40
    __shared__ float    linv[64];
    __shared__ float    WbL[CH];

    const int t = threadIdx.x;
    const int row = t >> 2, o8 = (t & 3) * 8;
    const int grow0 = blockIdx.x * 64;

    // stage Ww -> bf16 LDS (each thread: 8 contiguous o of row c=row)
    {
        const float* wp = Ww + row * CH2 + o8;
        ushort8v w;
        #pragma unroll
        for (int j = 0; j < 8; ++j) w[j] = f2bf_rne(wp[j]);
        *(ushort8v*)(&WwB[row * RPAD + o8]) = w;
    }
    if (t < CH) WbL[t] = Wb[t];
    if (t < 64) {
        float l = 0.f;
        for (int s = 0; s < nsplit; ++s) l += pl[(size_t)s * BN + grow0 + t];
        linv[t] = 1.0f / l;
    }

    // phase 1: sum splits (fully coalesced ushort8 loads)
    float acc[8];
    #pragma unroll
    for (int j = 0; j < 8; ++j) acc[j] = 0.f;
    for (int s = 0; s < nsplit; ++s) {
        ushort8v v = *(const ushort8v*)(py + ((size_t)s * BN + grow0 + row) * CH2 + o8);
        #pragma unroll
        for (int j = 0; j < 8; ++j)
            acc[j] += __uint_as_float((unsigned int)v[j] << 16);
    }
    __syncthreads();   // linv + WwB ready
    {
        float inv = linv[row];
        ushort8v yv;
        #pragma unroll
        for (int j = 0; j < 8; ++j) yv[j] = f2bf_rne(acc[j] * inv);
        *(ushort8v*)(&Y[row * RPAD + o8]) = yv;
    }
    __syncthreads();

    // phase 2: wave handles 16 rows x all 64 channels
    const int wave = t >> 6, lane = t & 63;
    const int ql = lane & 15, quad = lane >> 4;
    const int b = grow0 >> 12;                   // 64-row blocks never straddle batches
    const int nbase = (grow0 & (NN - 1)) + wave * 16;

    short8 bfrag = *(const short8*)(&Y[(wave * 16 + ql) * RPAD + quad * 8]);
    #pragma unroll
    for (int ct = 0; ct < 4; ++ct) {
        short8 afrag = *(const short8*)(&WwB[(ct * 16 + ql) * RPAD + quad * 8]);
        floatx4 d = (floatx4){0.f, 0.f, 0.f, 0.f};
        d = __builtin_amdgcn_mfma_f32_16x16x32_bf16(afrag, bfrag, d, 0, 0, 0);
        #pragma unroll
        for (int r = 0; r < 4; ++r) {
            int c = ct * 16 + quad * 4 + r;
            size_t oi = ((size_t)b * CH + c) * NN + nbase + ql;
            out[oi] = d[r] + WbL[c] + x[oi];     // 64B-coalesced segments
        }
    }
}

extern "C" void kernel_launch(void* const* d_in, const int* in_sizes, int n_in,
                              void* d_out, int out_size, void* d_ws, size_t ws_size,
                              hipStream_t stream) {
    const float* x  = (const float*)d_in[0];
    const float* gw = (const float*)d_in[1];
    const float* gb = (const float*)d_in[2];
    const float* Ww = (const float*)d_in[3];
    const float* Wb = (const float*)d_in[4];
    float* out = (float*)d_out;

    // workspace layout (kept small: harness re-poisons all of d_ws every launch)
    ushort_t* xT   = (ushort_t*)d_ws;                          // 4 MB
    ushort_t* gxT  = xT + (size_t)BN * CH;                     // 2 MB
    float*    mlog = (float*)(gxT + (size_t)BATCH * CH2 * NN); // 128 KB
    ushort_t* py   = (ushort_t*)(mlog + BN);                   // split*BN*32 bf16
    size_t base_bytes = (size_t)BN * CH * 2 + (size_t)BATCH * CH2 * NN * 2 + (size_t)BN * 4;
    int split = 4;
    while (split > 1 && base_bytes + (size_t)split * BN * (CH2 * 2 + 4) > ws_size)
        split >>= 1;
    float* pl = (float*)(py + (size_t)split * BN * CH2);

    hipLaunchKernelGGL(prep_fused,  dim3(BN * 4 / 256), dim3(256), 0, stream,
                       x, gw, gb, xT, mlog, gxT);
    hipLaunchKernelGGL(flash_attn,  dim3(256 * split),  dim3(256), 0, stream,
                       xT, gxT, mlog, py, pl, NN / split);
    hipLaunchKernelGGL(reduce_proj, dim3(BN / 64),      dim3(256), 0, stream,
                       py, pl, Ww, Wb, x, out, split);
}

// Round 8
// 122.339 us; speedup vs baseline: 1.4899x; 1.0346x over previous
//
#include <hip/hip_runtime.h>
#include <hip/hip_bf16.h>

#define BATCH 8
#define CH    64
#define CH2   32
#define NN    4096
#define BN    (BATCH * NN)   // 32768 rows total
#define KPAD  72             // LDS key-tile row stride (elements)
#define YPAD  36             // flash epilogue transpose row stride (floats)
#define RPAD  40             // reduce_proj LDS row stride (bf16 elements, 16B-aligned)

typedef __attribute__((ext_vector_type(8)))  short        short8;    // 8 bf16 (MFMA A/B frag)
typedef __attribute__((ext_vector_type(4)))  float        floatx4;   // 16x16 MFMA C/D frag
typedef __attribute__((ext_vector_type(16))) float        floatx16;  // 32x32 MFMA C/D frag
typedef __attribute__((ext_vector_type(4)))  unsigned int uint4v;
typedef __attribute__((ext_vector_type(8)))  unsigned short ushort8v;
typedef unsigned short ushort_t;

#define LOG2E      1.4426950408889634f
#define SQRT_LOG2E 1.2011224087864498f   // sqrt(log2(e)); Q,K both scaled -> S in log2 units

__device__ __forceinline__ unsigned short f2bf_rne(float f) {
    unsigned int u = __float_as_uint(f);
    return (unsigned short)((u + 0x7FFFu + ((u >> 16) & 1u)) >> 16);
}

// ---- fused prep: one pass over x produces
//   xT [B*N][64] bf16 = x * sqrt(log2e)  (so QK^T emerges pre-scaled by log2e),
//   mlog[row] = 12*||x_row||*log2e,
//   gxT [B][32 och][N] bf16 (V^T layout).
__global__ __launch_bounds__(256) void prep_fused(const float* __restrict__ x,
                                                  const float* __restrict__ gw,
                                                  const float* __restrict__ gb,
                                                  ushort_t* __restrict__ xT,
                                                  float* __restrict__ mlog,
                                                  ushort_t* __restrict__ gxT) {
    __shared__ float gwl[CH2 * CH];   // [o][c]
    __shared__ float gbl[CH2];
    int t = threadIdx.x;
    for (int i = t; i < CH2 * CH; i += 256) gwl[i] = gw[i];
    if (t < CH2) gbl[t] = gb[t];
    __syncthreads();

    int g   = blockIdx.x * 256 + t;
    int row = g >> 2;
    int q4  = g & 3;
    int b = row >> 12, n = row & (NN - 1);
    const float* xp = x + (size_t)b * CH * NN + n;

    float xv[16];
    float ns = 0.f;
    short8 v0, v1;
    #pragma unroll
    for (int j = 0; j < 8; ++j) {
        float a = xp[(size_t)(q4 * 16 + j) * NN];
        xv[j] = a; ns += a * a;
        v0[j] = (short)f2bf_rne(a * SQRT_LOG2E);
    }
    #pragma unroll
    for (int j = 0; j < 8; ++j) {
        float a = xp[(size_t)(q4 * 16 + 8 + j) * NN];
        xv[8 + j] = a; ns += a * a;
        v1[j] = (short)f2bf_rne(a * SQRT_LOG2E);
    }
    *(short8*)(xT + (size_t)row * CH + q4 * 16)     = v0;
    *(short8*)(xT + (size_t)row * CH + q4 * 16 + 8) = v1;
    ns += __shfl_xor(ns, 1);
    ns += __shfl_xor(ns, 2);
    if (q4 == 0) mlog[row] = 12.0f * sqrtf(ns) * LOG2E;

    float acc[CH2];
    #pragma unroll
    for (int o = 0; o < CH2; ++o) acc[o] = 0.f;
    #pragma unroll
    for (int j = 0; j < 16; ++j) {
        float a = xv[j];
        const float* gc = gwl + q4 * 16 + j;
        #pragma unroll
        for (int o = 0; o < CH2; ++o) acc[o] = fmaf(gc[o * CH], a, acc[o]);
    }
    #pragma unroll
    for (int o = 0; o < CH2; ++o) {
        acc[o] += __shfl_xor(acc[o], 1);
        acc[o] += __shfl_xor(acc[o], 2);
    }
    #pragma unroll
    for (int i = 0; i < 8; ++i) {
        int o = q4 * 8 + i;
        gxT[((size_t)b * CH2 + o) * NN + n] = f2bf_rne(acc[o] + gbl[o]);
    }
}

// ---- flash attention, S^T formulation (32x32x16 MFMA):
//   S^T = K·Q^T with accumulator pre-initialized to -ml (inputs pre-scaled by
//   sqrt(log2e)) -> P = exp2(st) directly, zero VALU prep per element.
//   l accumulated on the MFMA pipe via a ones-A-operand C-frag.
//   P^T B-operand built in-register (pack via v_perm + shfl_xor(32) butterfly).
// LDS: K tile, aliased with the epilogue transpose buffer (18.4 KB total).
__global__ __launch_bounds__(256, 4) void flash_attn(const ushort_t* __restrict__ xT,
                                                     const ushort_t* __restrict__ gxT,
                                                     const float* __restrict__ mlog,
                                                     ushort_t* __restrict__ py,
                                                     float* __restrict__ pl,
                                                     int ksplit) {
    __shared__ __align__(16) unsigned char smem[4 * 32 * YPAD * 4];  // 18432 B
    ushort_t* Klds = (ushort_t*)smem;                                // 9216 B during K-loop

    const int tid = threadIdx.x, wave = tid >> 6, lane = tid & 63;
    const int q5 = lane & 31;
    const int h  = lane >> 5;
    const int bq = blockIdx.x & 255;
    const int sp = blockIdx.x >> 8;
    const int b = bq >> 5, qt = bq & 31;
    const int n0 = qt * 128 + wave * 32;
    const int k0 = sp * ksplit;

    short8 qf[4];
    {
        const ushort_t* qp = xT + ((size_t)(b * NN + n0 + q5)) * CH + h * 8;
        #pragma unroll
        for (int f = 0; f < 4; ++f) qf[f] = *(const short8*)(qp + f * 16);
    }
    const float ml = mlog[(size_t)b * NN + n0 + q5];

    short8 ones;
    #pragma unroll
    for (int j = 0; j < 8; ++j) ones[j] = (short)0x3F80;   // bf16 1.0

    floatx16 yt, lt;
    #pragma unroll
    for (int i = 0; i < 16; ++i) { yt[i] = 0.f; lt[i] = 0.f; }

    const ushort_t* kb = xT + (size_t)(b * NN + k0) * CH;
    const ushort_t* vb = gxT + (size_t)b * CH2 * NN + k0;
    const int iters = ksplit >> 6;
    const int skey = tid >> 3, sc0 = (tid & 7) * 8;

    for (int kt = 0; kt < iters; ++kt) {
        short8 kv0 = *(const short8*)(kb + ((size_t)kt << 12) + (size_t)skey * CH + sc0);
        short8 kv1 = *(const short8*)(kb + ((size_t)kt << 12) + (size_t)(skey + 32) * CH + sc0);
        short8 vf[4];
        #pragma unroll
        for (int fr = 0; fr < 4; ++fr)
            vf[fr] = *(const short8*)(vb + (size_t)q5 * NN + kt * 64 + fr * 16 + h * 8);

        __syncthreads();
        *(short8*)(&Klds[skey * KPAD + sc0])        = kv0;
        *(short8*)(&Klds[(skey + 32) * KPAD + sc0]) = kv1;
        __syncthreads();

        #pragma unroll
        for (int T = 0; T < 2; ++T) {
            floatx16 st;
            #pragma unroll
            for (int i = 0; i < 16; ++i) st[i] = -ml;    // softmax shift folded into C-init
            #pragma unroll
            for (int f = 0; f < 4; ++f) {
                short8 kf = *(const short8*)(&Klds[(T * 32 + q5) * KPAD + f * 16 + h * 8]);
                st = __builtin_amdgcn_mfma_f32_32x32x16_bf16(kf, qf[f], st, 0, 0, 0);
            }
            // P = exp2(st); pack pairs round-half-up via v_perm (3 VALU/pair)
            unsigned int d[8];
            #pragma unroll
            for (int r2 = 0; r2 < 8; ++r2) {
                float p0 = __builtin_amdgcn_exp2f(st[2 * r2]);
                float p1 = __builtin_amdgcn_exp2f(st[2 * r2 + 1]);
                unsigned int u0 = __float_as_uint(p0) + 0x8000u;
                unsigned int u1 = __float_as_uint(p1) + 0x8000u;
                d[r2] = __builtin_amdgcn_perm(u1, u0, 0x07060302u);
            }
            // P^T B-frags: butterfly across lane^32 + select
            #pragma unroll
            for (int fp = 0; fp < 2; ++fp) {
                unsigned int d0 = d[fp * 4 + 0], d1 = d[fp * 4 + 1];
                unsigned int d2 = d[fp * 4 + 2], d3 = d[fp * 4 + 3];
                unsigned int e0 = (unsigned int)__shfl_xor((int)d0, 32);
                unsigned int e1 = (unsigned int)__shfl_xor((int)d1, 32);
                unsigned int e2 = (unsigned int)__shfl_xor((int)d2, 32);
                unsigned int e3 = (unsigned int)__shfl_xor((int)d3, 32);
                uint4v bv;
                bv[0] = h ? e2 : d0;
                bv[1] = h ? e3 : d1;
                bv[2] = h ? d2 : e0;
                bv[3] = h ? d3 : e1;
                short8 pb = __builtin_bit_cast(short8, bv);
                yt = __builtin_amdgcn_mfma_f32_32x32x16_bf16(vf[T * 2 + fp], pb, yt, 0, 0, 0);
                lt = __builtin_amdgcn_mfma_f32_32x32x16_bf16(ones, pb, lt, 0, 0, 0);
            }
        }
    }

    // epilogue: transpose y^T via LDS (aliased over Klds — barrier first)
    __syncthreads();
    float* yb = (float*)smem + wave * 32 * YPAD;
    #pragma unroll
    for (int reg = 0; reg < 16; ++reg) {
        int o = (reg & 3) + 8 * (reg >> 2) + 4 * h;
        yb[q5 * YPAD + o] = yt[reg];
    }
    __syncthreads();
    {
        int qq = lane >> 1, half = lane & 1;
        const float* src = yb + qq * YPAD + half * 16;
        float4 s0 = *(const float4*)(src);
        float4 s1 = *(const float4*)(src + 4);
        float4 s2 = *(const float4*)(src + 8);
        float4 s3 = *(const float4*)(src + 12);
        ushort8v pk0, pk1;
        pk0[0] = f2bf_rne(s0.x); pk0[1] = f2bf_rne(s0.y);
        pk0[2] = f2bf_rne(s0.z); pk0[3] = f2bf_rne(s0.w);
        pk0[4] = f2bf_rne(s1.x); pk0[5] = f2bf_rne(s1.y);
        pk0[6] = f2bf_rne(s1.z); pk0[7] = f2bf_rne(s1.w);
        pk1[0] = f2bf_rne(s2.x); pk1[1] = f2bf_rne(s2.y);
        pk1[2] = f2bf_rne(s2.z); pk1[3] = f2bf_rne(s2.w);
        pk1[4] = f2bf_rne(s3.x); pk1[5] = f2bf_rne(s3.y);
        pk1[6] = f2bf_rne(s3.z); pk1[7] = f2bf_rne(s3.w);
        ushort_t* dst = py + ((size_t)sp * BN + (size_t)b * NN + n0 + qq) * CH2 + half * 16;
        *(ushort8v*)(dst)     = pk0;
        *(ushort8v*)(dst + 8) = pk1;
    }
    // l: every lt row holds the full key-sum for column q5
    if (h == 0) pl[(size_t)sp * BN + (size_t)b * NN + n0 + q5] = lt[0];
}

// ---- reduce+proj: two-phase, MFMA projection (unchanged from R7).
__global__ __launch_bounds__(256) void reduce_proj(const ushort_t* __restrict__ py,
                                                   const float* __restrict__ pl,
                                                   const float* __restrict__ Ww,
                                                   const float* __restrict__ Wb,
                                                   const float* __restrict__ x,
                                                   float* __restrict__ out,
                                                   int nsplit) {
    __shared__ ushort_t WwB[CH * RPAD];
    __shared__ ushort_t Y[64 * RPAD];
    __shared__ float    linv[64];
    __shared__ float    WbL[CH];

    const int t = threadIdx.x;
    const int row = t >> 2, o8 = (t & 3) * 8;
    const int grow0 = blockIdx.x * 64;

    {
        const float* wp = Ww + row * CH2 + o8;
        ushort8v w;
        #pragma unroll
        for (int j = 0; j < 8; ++j) w[j] = f2bf_rne(wp[j]);
        *(ushort8v*)(&WwB[row * RPAD + o8]) = w;
    }
    if (t < CH) WbL[t] = Wb[t];
    if (t < 64) {
        float l = 0.f;
        for (int s = 0; s < nsplit; ++s) l += pl[(size_t)s * BN + grow0 + t];
        linv[t] = 1.0f / l;
    }

    float acc[8];
    #pragma unroll
    for (int j = 0; j < 8; ++j) acc[j] = 0.f;
    for (int s = 0; s < nsplit; ++s) {
        ushort8v v = *(const ushort8v*)(py + ((size_t)s * BN + grow0 + row) * CH2 + o8);
        #pragma unroll
        for (int j = 0; j < 8; ++j)
            acc[j] += __uint_as_float((unsigned int)v[j] << 16);
    }
    __syncthreads();
    {
        float inv = linv[row];
        ushort8v yv;
        #pragma unroll
        for (int j = 0; j < 8; ++j) yv[j] = f2bf_rne(acc[j] * inv);
        *(ushort8v*)(&Y[row * RPAD + o8]) = yv;
    }
    __syncthreads();

    const int wave = t >> 6, lane = t & 63;
    const int ql = lane & 15, quad = lane >> 4;
    const int b = grow0 >> 12;
    const int nbase = (grow0 & (NN - 1)) + wave * 16;

    short8 bfrag = *(const short8*)(&Y[(wave * 16 + ql) * RPAD + quad * 8]);
    #pragma unroll
    for (int ct = 0; ct < 4; ++ct) {
        short8 afrag = *(const short8*)(&WwB[(ct * 16 + ql) * RPAD + quad * 8]);
        floatx4 d = (floatx4){0.f, 0.f, 0.f, 0.f};
        d = __builtin_amdgcn_mfma_f32_16x16x32_bf16(afrag, bfrag, d, 0, 0, 0);
        #pragma unroll
        for (int r = 0; r < 4; ++r) {
            int c = ct * 16 + quad * 4 + r;
            size_t oi = ((size_t)b * CH + c) * NN + nbase + ql;
            out[oi] = d[r] + WbL[c] + x[oi];
        }
    }
}

extern "C" void kernel_launch(void* const* d_in, const int* in_sizes, int n_in,
                              void* d_out, int out_size, void* d_ws, size_t ws_size,
                              hipStream_t stream) {
    const float* x  = (const float*)d_in[0];
    const float* gw = (const float*)d_in[1];
    const float* gb = (const float*)d_in[2];
    const float* Ww = (const float*)d_in[3];
    const float* Wb = (const float*)d_in[4];
    float* out = (float*)d_out;

    ushort_t* xT   = (ushort_t*)d_ws;                          // 4 MB
    ushort_t* gxT  = xT + (size_t)BN * CH;                     // 2 MB
    float*    mlog = (float*)(gxT + (size_t)BATCH * CH2 * NN); // 128 KB
    ushort_t* py   = (ushort_t*)(mlog + BN);                   // split*BN*32 bf16
    size_t base_bytes = (size_t)BN * CH * 2 + (size_t)BATCH * CH2 * NN * 2 + (size_t)BN * 4;
    int split = 4;
    while (split > 1 && base_bytes + (size_t)split * BN * (CH2 * 2 + 4) > ws_size)
        split >>= 1;
    float* pl = (float*)(py + (size_t)split * BN * CH2);

    hipLaunchKernelGGL(prep_fused,  dim3(BN * 4 / 256), dim3(256), 0, stream,
                       x, gw, gb, xT, mlog, gxT);
    hipLaunchKernelGGL(flash_attn,  dim3(256 * split),  dim3(256), 0, stream,
                       xT, gxT, mlog, py, pl, NN / split);
    hipLaunchKernelGGL(reduce_proj, dim3(BN / 64),      dim3(256), 0, stream,
                       py, pl, Ww, Wb, x, out, split);
}